// Round 1
// baseline (343.560 us; speedup 1.0000x reference)
//
#include <hip/hip_runtime.h>
#include <stdint.h>

#define HID   1024
#define NH    16
#define HD    64
#define BATCH 2
#define SEQ   2048
#define MROWS (BATCH*SEQ)
#define ATT_SCALE 0.125f

typedef __attribute__((ext_vector_type(4))) float f32x4;
typedef __attribute__((ext_vector_type(8))) short bf16x8;
typedef unsigned short u16;
typedef __attribute__((ext_vector_type(4))) unsigned short u16x4;

// fp32 -> bf16 round-to-nearest-even, raw bits
__device__ __forceinline__ u16 f2b(float f) {
  union { float f; unsigned u; } c; c.f = f;
  unsigned u = c.u;
  return (u16)((u + 0x7fffu + ((u >> 16) & 1u)) >> 16);
}

// async global -> LDS, 16 bytes per lane (wave-uniform LDS base + lane*16)
__device__ __forceinline__ void gload16(const void* g, void* l) {
  __builtin_amdgcn_global_load_lds((__attribute__((address_space(1))) void*)g,
                                   (__attribute__((address_space(3))) void*)l,
                                   16, 0, 0);
}

// ---------------------------------------------------------------- cast X
__global__ void castx_kernel(const float* __restrict__ X, u16* __restrict__ XB) {
  const int i = blockIdx.x * blockDim.x + threadIdx.x;
  const float4 v = ((const float4*)X)[i];
  u16x4 o = { f2b(v.x), f2b(v.y), f2b(v.z), f2b(v.w) };
  ((u16x4*)XB)[i] = o;
}

// ------------------------------------------------- transpose-cast W -> W^T
__global__ void wtrans_kernel(const float* __restrict__ W, u16* __restrict__ Wt) {
  __shared__ u16 tile[32][33];
  const int bx = blockIdx.x * 32;  // n base (cols of W)
  const int by = blockIdx.y * 32;  // k base (rows of W)
  const int tx = threadIdx.x, ty = threadIdx.y;
#pragma unroll
  for (int i = 0; i < 4; ++i)
    tile[ty + i * 8][tx] = f2b(W[(size_t)(by + ty + i * 8) * HID + bx + tx]);
  __syncthreads();
#pragma unroll
  for (int i = 0; i < 4; ++i)
    Wt[(size_t)(bx + ty + i * 8) * HID + by + tx] = tile[tx][ty + i * 8];
}

// ---------------------------------------------------------------- GEMM
// A: [MROWS][HID] bf16 row-major. Bt: [N=HID][K=HID] bf16 (W transposed).
// MODE 0: store bf16 into [B,NH,S,HD]   (Q, K)
// MODE 2: store bf16 into [B,NH,HD,S]   (V transposed)
// MODE 3: store fp32 into [MROWS][HID]  (final output)
template <int MODE>
__global__ __launch_bounds__(256) void gemm_kernel(const u16* __restrict__ A,
                                                   const u16* __restrict__ Bt,
                                                   const float* __restrict__ bias,
                                                   void* __restrict__ Cout) {
  __shared__ u16 Asm[128 * 64];
  __shared__ u16 Bsm[128 * 64];
  const int tid = threadIdx.x;
  const int lane = tid & 63;
  const int wid = tid >> 6;
  const int wr = wid >> 1, wc = wid & 1;   // 2x2 waves, 64x64 each
  const int m0 = blockIdx.x * 128;
  const int n0 = blockIdx.y * 128;
  const int lrow = lane & 15;
  const int kgrp = (lane >> 4) * 8;

  f32x4 acc[4][4];
#pragma unroll
  for (int i = 0; i < 4; ++i)
#pragma unroll
    for (int j = 0; j < 4; ++j)
#pragma unroll
      for (int r = 0; r < 4; ++r) acc[i][j][r] = 0.f;

  for (int kt = 0; kt < HID / 64; ++kt) {
    __syncthreads();
#pragma unroll
    for (int it = 0; it < 4; ++it) {
      const int off = it * 4096 + tid * 16;   // byte offset in 16KB tile
      const int row = off >> 7;               // 128B per row
      const int col = (off & 127) >> 1;       // ushort col
      gload16(A  + (size_t)(m0 + row) * HID + kt * 64 + col, (char*)Asm + off);
      gload16(Bt + (size_t)(n0 + row) * HID + kt * 64 + col, (char*)Bsm + off);
    }
    __syncthreads();
#pragma unroll
    for (int kk = 0; kk < 2; ++kk) {
      bf16x8 af[4], bfr[4];
#pragma unroll
      for (int i = 0; i < 4; ++i) {
        af[i]  = *(const bf16x8*)(Asm + (size_t)(wr * 64 + i * 16 + lrow) * 64 + kk * 32 + kgrp);
        bfr[i] = *(const bf16x8*)(Bsm + (size_t)(wc * 64 + i * 16 + lrow) * 64 + kk * 32 + kgrp);
      }
#pragma unroll
      for (int i = 0; i < 4; ++i)
#pragma unroll
        for (int j = 0; j < 4; ++j)
          acc[i][j] = __builtin_amdgcn_mfma_f32_16x16x32_bf16(af[i], bfr[j], acc[i][j], 0, 0, 0);
    }
  }

  // epilogue: C row = (lane>>4)*4 + r, col = lane&15 within each 16x16 frag
#pragma unroll
  for (int i = 0; i < 4; ++i) {
#pragma unroll
    for (int j = 0; j < 4; ++j) {
      const int rbase = m0 + wr * 64 + i * 16 + (lane >> 4) * 4;
      const int n = n0 + wc * 64 + j * 16 + lrow;
      const float bv = bias[n];
      if (MODE == 3) {
        float* O = (float*)Cout;
#pragma unroll
        for (int r = 0; r < 4; ++r)
          O[(size_t)(rbase + r) * HID + n] = acc[i][j][r] + bv;
      } else if (MODE == 0) {
        u16* O = (u16*)Cout;
        const int h = n >> 6, d = n & 63;
#pragma unroll
        for (int r = 0; r < 4; ++r) {
          const int m = rbase + r;
          const int b = m >> 11, s = m & 2047;
          O[((size_t)(b * NH + h) * SEQ + s) * HD + d] = f2b(acc[i][j][r] + bv);
        }
      } else {  // MODE 2: V^T  [B,NH,HD,S]
        u16* O = (u16*)Cout;
        const int h = n >> 6, d = n & 63;
        const int b = rbase >> 11, s = rbase & 2047;
        u16x4 pk;
#pragma unroll
        for (int r = 0; r < 4; ++r) pk[r] = f2b(acc[i][j][r] + bv);
        *(u16x4*)(O + ((size_t)(b * NH + h) * HD + d) * SEQ + s) = pk;
      }
    }
  }
}

// ------------------------------------------------------------ flash attention
// Q,K: [B,NH,S,HD] bf16; Vt: [B,NH,HD,S] bf16; msk: [B,S] f32
// ctx out: [B,S,HID] bf16
__global__ __launch_bounds__(256) void attn_kernel(const u16* __restrict__ Q,
                                                   const u16* __restrict__ K,
                                                   const u16* __restrict__ Vt,
                                                   const float* __restrict__ msk,
                                                   u16* __restrict__ ctx) {
  __shared__ u16 Ks[64 * 64];       // [key][d]
  __shared__ u16 Vs[64 * 64];       // [d][key]
  __shared__ u16 Ps[4][32 * 72];    // per-wave P, padded rows (72) = conflict-light
  const int bh = blockIdx.y;
  const int b = bh >> 4, h = bh & 15;
  const int q0 = blockIdx.x * 128;
  const int tid = threadIdx.x, lane = tid & 63, wid = tid >> 6;
  const int lrow = lane & 15;
  const int kgrp = (lane >> 4) * 8;
  const u16* Qp = Q + (size_t)bh * SEQ * HD;
  const u16* Kp = K + (size_t)bh * SEQ * HD;
  const u16* Vp = Vt + (size_t)bh * HD * SEQ;

  // Q fragments in registers, reused for all key tiles. Wave owns 32 q-rows.
  bf16x8 qf[2][2];
#pragma unroll
  for (int rf = 0; rf < 2; ++rf)
#pragma unroll
    for (int kk = 0; kk < 2; ++kk)
      qf[rf][kk] = *(const bf16x8*)(Qp + (size_t)(q0 + wid * 32 + rf * 16 + lrow) * HD + kk * 32 + kgrp);

  float mrun[2][4], lrun[2][4];
  f32x4 acc[2][4];
#pragma unroll
  for (int rf = 0; rf < 2; ++rf)
#pragma unroll
    for (int r = 0; r < 4; ++r) { mrun[rf][r] = -3.0e38f; lrun[rf][r] = 0.f; }
#pragma unroll
  for (int rf = 0; rf < 2; ++rf)
#pragma unroll
    for (int df = 0; df < 4; ++df)
#pragma unroll
      for (int r = 0; r < 4; ++r) acc[rf][df][r] = 0.f;

  for (int s0 = 0; s0 < SEQ; s0 += 64) {
    __syncthreads();  // all waves done with previous K/V tiles
#pragma unroll
    for (int it = 0; it < 2; ++it) {
      const int off = it * 4096 + tid * 16;
      const int row = off >> 7;
      const int col = (off & 127) >> 1;
      gload16(Kp + (size_t)(s0 + row) * HD + col, (char*)Ks + off);
      gload16(Vp + (size_t)row * SEQ + s0 + col, (char*)Vs + off);
    }
    __syncthreads();  // staging complete (barrier drains vmcnt)

    // S = Q K^T
    f32x4 sf[2][4];
#pragma unroll
    for (int rf = 0; rf < 2; ++rf)
#pragma unroll
      for (int c = 0; c < 4; ++c)
#pragma unroll
        for (int r = 0; r < 4; ++r) sf[rf][c][r] = 0.f;
#pragma unroll
    for (int kk = 0; kk < 2; ++kk) {
      bf16x8 kf[4];
#pragma unroll
      for (int c = 0; c < 4; ++c)
        kf[c] = *(const bf16x8*)(Ks + (size_t)(c * 16 + lrow) * 64 + kk * 32 + kgrp);
#pragma unroll
      for (int rf = 0; rf < 2; ++rf)
#pragma unroll
        for (int c = 0; c < 4; ++c)
          sf[rf][c] = __builtin_amdgcn_mfma_f32_16x16x32_bf16(qf[rf][kk], kf[c], sf[rf][c], 0, 0, 0);
    }

    // scale + additive mask (column-wise)
    float addm[4];
#pragma unroll
    for (int c = 0; c < 4; ++c)
      addm[c] = (1.0f - msk[b * SEQ + s0 + c * 16 + lrow]) * -10000.0f;
#pragma unroll
    for (int rf = 0; rf < 2; ++rf)
#pragma unroll
      for (int c = 0; c < 4; ++c)
#pragma unroll
        for (int r = 0; r < 4; ++r)
          sf[rf][c][r] = sf[rf][c][r] * ATT_SCALE + addm[c];

    // online softmax (rows live on 16-lane groups; reduce with shfl_xor w16)
#pragma unroll
    for (int rf = 0; rf < 2; ++rf) {
      float alpha[4];
#pragma unroll
      for (int r = 0; r < 4; ++r) {
        float mx = fmaxf(fmaxf(sf[rf][0][r], sf[rf][1][r]),
                         fmaxf(sf[rf][2][r], sf[rf][3][r]));
#pragma unroll
        for (int o = 1; o < 16; o <<= 1) mx = fmaxf(mx, __shfl_xor(mx, o, 16));
        const float mn = fmaxf(mrun[rf][r], mx);
        const float al = __expf(mrun[rf][r] - mn);
        mrun[rf][r] = mn;
        float rs = 0.f;
#pragma unroll
        for (int c = 0; c < 4; ++c) {
          const float p = __expf(sf[rf][c][r] - mn);
          sf[rf][c][r] = p;
          rs += p;
        }
#pragma unroll
        for (int o = 1; o < 16; o <<= 1) rs += __shfl_xor(rs, o, 16);
        lrun[rf][r] = lrun[rf][r] * al + rs;
        alpha[r] = al;
      }
#pragma unroll
      for (int df = 0; df < 4; ++df)
#pragma unroll
        for (int r = 0; r < 4; ++r) acc[rf][df][r] *= alpha[r];
      // P (C-layout) -> per-wave LDS, bf16
#pragma unroll
      for (int c = 0; c < 4; ++c)
#pragma unroll
        for (int r = 0; r < 4; ++r)
          Ps[wid][(size_t)(rf * 16 + (lane >> 4) * 4 + r) * 72 + c * 16 + lrow] =
              f2b(sf[rf][c][r]);
    }

    // ctx += P V  (A-frags re-read from own wave's Ps; no barrier needed)
#pragma unroll
    for (int kk = 0; kk < 2; ++kk) {
      bf16x8 pf[2], vf[4];
#pragma unroll
      for (int rf = 0; rf < 2; ++rf)
        pf[rf] = *(const bf16x8*)(&Ps[wid][(size_t)(rf * 16 + lrow) * 72 + kk * 32 + kgrp]);
#pragma unroll
      for (int df = 0; df < 4; ++df)
        vf[df] = *(const bf16x8*)(Vs + (size_t)(df * 16 + lrow) * 64 + kk * 32 + kgrp);
#pragma unroll
      for (int rf = 0; rf < 2; ++rf)
#pragma unroll
        for (int df = 0; df < 4; ++df)
          acc[rf][df] = __builtin_amdgcn_mfma_f32_16x16x32_bf16(pf[rf], vf[df], acc[rf][df], 0, 0, 0);
    }
  }

  // normalize + store ctx in [B,S,HID] bf16
#pragma unroll
  for (int rf = 0; rf < 2; ++rf)
#pragma unroll
    for (int df = 0; df < 4; ++df)
#pragma unroll
      for (int r = 0; r < 4; ++r) {
        const int s = q0 + wid * 32 + rf * 16 + (lane >> 4) * 4 + r;
        const int d = df * 16 + lrow;
        const float v = acc[rf][df][r] / lrun[rf][r];
        ctx[((size_t)(b * SEQ + s)) * HID + h * HD + d] = f2b(v);
      }
}

// ---------------------------------------------------------------- launch
extern "C" void kernel_launch(void* const* d_in, const int* in_sizes, int n_in,
                              void* d_out, int out_size, void* d_ws, size_t ws_size,
                              hipStream_t stream) {
  const float* X    = (const float*)d_in[0];
  const float* msk  = (const float*)d_in[1];
  const float* Wq   = (const float*)d_in[2];
  const float* bq   = (const float*)d_in[3];
  const float* Wk   = (const float*)d_in[4];
  const float* bk   = (const float*)d_in[5];
  const float* Wv   = (const float*)d_in[6];
  const float* bv   = (const float*)d_in[7];
  const float* Wo   = (const float*)d_in[8];
  const float* bo   = (const float*)d_in[9];
  float* out = (float*)d_out;
  char* ws = (char*)d_ws;

  const size_t MB = 1u << 20;
  u16* XB   = (u16*)(ws);              //  8 MB  [MROWS][HID]
  u16* WTq  = (u16*)(ws +  8 * MB);    //  2 MB each
  u16* WTk  = (u16*)(ws + 10 * MB);
  u16* WTv  = (u16*)(ws + 12 * MB);
  u16* WTo  = (u16*)(ws + 14 * MB);
  u16* Qb   = (u16*)(ws + 16 * MB);    //  8 MB  [B,NH,S,HD]
  u16* Kb   = (u16*)(ws + 24 * MB);    //  8 MB  [B,NH,S,HD]
  u16* VTb  = (u16*)(ws + 32 * MB);    //  8 MB  [B,NH,HD,S]
  u16* CTXb = (u16*)(ws + 40 * MB);    //  8 MB  [B,S,HID]

  castx_kernel<<<dim3(MROWS * HID / 4 / 256), dim3(256), 0, stream>>>(X, XB);

  dim3 tb(32, 8), tg(HID / 32, HID / 32);
  wtrans_kernel<<<tg, tb, 0, stream>>>(Wq, WTq);
  wtrans_kernel<<<tg, tb, 0, stream>>>(Wk, WTk);
  wtrans_kernel<<<tg, tb, 0, stream>>>(Wv, WTv);
  wtrans_kernel<<<tg, tb, 0, stream>>>(Wo, WTo);

  dim3 gg(MROWS / 128, HID / 128);
  gemm_kernel<0><<<gg, dim3(256), 0, stream>>>(XB, WTq, bq, Qb);
  gemm_kernel<0><<<gg, dim3(256), 0, stream>>>(XB, WTk, bk, Kb);
  gemm_kernel<2><<<gg, dim3(256), 0, stream>>>(XB, WTv, bv, VTb);

  attn_kernel<<<dim3(SEQ / 128, BATCH * NH), dim3(256), 0, stream>>>(Qb, Kb, VTb, msk, CTXb);

  gemm_kernel<3><<<gg, dim3(256), 0, stream>>>(CTXb, WTo, bo, out);
}

// Round 3
// 241.656 us; speedup vs baseline: 1.4217x; 1.4217x over previous
//
#include <hip/hip_runtime.h>
#include <hip/hip_bf16.h>
#include <stdint.h>

#define HID   1024
#define NH    16
#define HD    64
#define BATCH 2
#define SEQ   2048
#define MROWS (BATCH*SEQ)
#define ATT_SCALE 0.125f

typedef __attribute__((ext_vector_type(4))) float f32x4;
typedef __attribute__((ext_vector_type(8))) short bf16x8;
typedef unsigned short u16;
typedef __attribute__((ext_vector_type(4))) unsigned short u16x4;

// fp32 -> bf16 round-to-nearest-even, raw bits
__device__ __forceinline__ u16 f2b(float f) {
  union { float f; unsigned u; } c; c.f = f;
  unsigned u = c.u;
  return (u16)((u + 0x7fffu + ((u >> 16) & 1u)) >> 16);
}

// packed f32x2 -> bf16x2 via documented HIP API (guaranteed packing: x=lo, y=hi)
__device__ __forceinline__ unsigned pk2(float a, float b) {
  union { __hip_bfloat162 h; unsigned u; } c;
  c.h = __float22bfloat162_rn(make_float2(a, b));
  return c.u;
}

// async global -> LDS, 16 bytes per lane (wave-uniform LDS base + lane*16)
__device__ __forceinline__ void gload16(const void* g, void* l) {
  __builtin_amdgcn_global_load_lds((__attribute__((address_space(1))) void*)g,
                                   (__attribute__((address_space(3))) void*)l,
                                   16, 0, 0);
}

// ---------------------------------------------------------------- cast X
__global__ void castx_kernel(const float* __restrict__ X, u16* __restrict__ XB) {
  const int i = blockIdx.x * blockDim.x + threadIdx.x;
  const float4 v = ((const float4*)X)[i];
  u16x4 o = { f2b(v.x), f2b(v.y), f2b(v.z), f2b(v.w) };
  ((u16x4*)XB)[i] = o;
}

// ------------------------------------------------- transpose-cast 4x W -> W^T
__global__ void wtrans4_kernel(const float* w0, const float* w1,
                               const float* w2, const float* w3,
                               u16* o0, u16* o1, u16* o2, u16* o3) {
  __shared__ u16 tile[32][33];
  const int z = blockIdx.z;
  const float* __restrict__ W = (z == 0) ? w0 : (z == 1) ? w1 : (z == 2) ? w2 : w3;
  u16* __restrict__ Wt = (z == 0) ? o0 : (z == 1) ? o1 : (z == 2) ? o2 : o3;
  const int bx = blockIdx.x * 32;  // n base (cols of W)
  const int by = blockIdx.y * 32;  // k base (rows of W)
  const int tx = threadIdx.x, ty = threadIdx.y;
#pragma unroll
  for (int i = 0; i < 4; ++i)
    tile[ty + i * 8][tx] = f2b(W[(size_t)(by + ty + i * 8) * HID + bx + tx]);
  __syncthreads();
#pragma unroll
  for (int i = 0; i < 4; ++i)
    Wt[(size_t)(bx + ty + i * 8) * HID + by + tx] = tile[tx][ty + i * 8];
}

// ------------------------------------------------------- fused QKV GEMM
// A: [MROWS][HID] bf16. Bt: [3072][HID] bf16 (WTq|WTk|WTv contiguous).
// n in [0,1024) -> Q [B,NH,S,HD]; [1024,2048) -> K same; [2048,3072) -> V^T [B,NH,HD,S]
__global__ __launch_bounds__(256) void gemm_qkv_kernel(const u16* __restrict__ A,
                                                       const u16* __restrict__ Bt,
                                                       const float* __restrict__ bq,
                                                       const float* __restrict__ bk,
                                                       const float* __restrict__ bv,
                                                       u16* __restrict__ Qb,
                                                       u16* __restrict__ Kb,
                                                       u16* __restrict__ VTb) {
  __shared__ u16 Asm[128 * 64];
  __shared__ u16 Bsm[128 * 64];
  const int tid = threadIdx.x;
  const int lane = tid & 63;
  const int wid = tid >> 6;
  const int wr = wid >> 1, wc = wid & 1;   // 2x2 waves, 64x64 each
  const int m0 = blockIdx.x * 128;
  const int n0 = blockIdx.y * 128;
  const int mat = n0 >> 10;                // 0=Q 1=K 2=V (uniform per block)
  const int lrow = lane & 15;
  const int kgrp = (lane >> 4) * 8;

  f32x4 acc[4][4];
#pragma unroll
  for (int i = 0; i < 4; ++i)
#pragma unroll
    for (int j = 0; j < 4; ++j)
#pragma unroll
      for (int r = 0; r < 4; ++r) acc[i][j][r] = 0.f;

  for (int kt = 0; kt < HID / 64; ++kt) {
    __syncthreads();
#pragma unroll
    for (int it = 0; it < 4; ++it) {
      const int off = it * 4096 + tid * 16;   // byte offset in 16KB tile
      const int row = off >> 7;               // 128B per row
      const int col = (off & 127) >> 1;       // ushort col
      gload16(A  + (size_t)(m0 + row) * HID + kt * 64 + col, (char*)Asm + off);
      gload16(Bt + (size_t)(n0 + row) * HID + kt * 64 + col, (char*)Bsm + off);
    }
    __syncthreads();
#pragma unroll
    for (int kk = 0; kk < 2; ++kk) {
      bf16x8 af[4], bfr[4];
#pragma unroll
      for (int i = 0; i < 4; ++i) {
        af[i]  = *(const bf16x8*)(Asm + (size_t)(wr * 64 + i * 16 + lrow) * 64 + kk * 32 + kgrp);
        bfr[i] = *(const bf16x8*)(Bsm + (size_t)(wc * 64 + i * 16 + lrow) * 64 + kk * 32 + kgrp);
      }
#pragma unroll
      for (int i = 0; i < 4; ++i)
#pragma unroll
        for (int j = 0; j < 4; ++j)
          acc[i][j] = __builtin_amdgcn_mfma_f32_16x16x32_bf16(af[i], bfr[j], acc[i][j], 0, 0, 0);
    }
  }

  const float* bias = (mat == 0) ? bq : (mat == 1) ? bk : bv;
  u16* O = (mat == 0) ? Qb : (mat == 1) ? Kb : VTb;
#pragma unroll
  for (int i = 0; i < 4; ++i) {
#pragma unroll
    for (int j = 0; j < 4; ++j) {
      const int rbase = m0 + wr * 64 + i * 16 + (lane >> 4) * 4;
      const int n = n0 + wc * 64 + j * 16 + lrow;
      const int nl = n & 1023;
      const float bv_ = bias[nl];
      const int h = nl >> 6, d = nl & 63;
      if (mat != 2) {
#pragma unroll
        for (int r = 0; r < 4; ++r) {
          const int m = rbase + r;
          const int b = m >> 11, s = m & 2047;
          O[((size_t)(b * NH + h) * SEQ + s) * HD + d] = f2b(acc[i][j][r] + bv_);
        }
      } else {  // V^T  [B,NH,HD,S]
        const int b = rbase >> 11, s = rbase & 2047;
        u16x4 pk;
#pragma unroll
        for (int r = 0; r < 4; ++r) pk[r] = f2b(acc[i][j][r] + bv_);
        *(u16x4*)(O + ((size_t)(b * NH + h) * HD + d) * SEQ + s) = pk;
      }
    }
  }
}

// ---------------------------------------------------------------- out GEMM
// A: [MROWS][HID] bf16 (ctx). Bt: [HID][HID] bf16 (Wo^T). fp32 out.
__global__ __launch_bounds__(256) void gemm_out_kernel(const u16* __restrict__ A,
                                                       const u16* __restrict__ Bt,
                                                       const float* __restrict__ bias,
                                                       float* __restrict__ O) {
  __shared__ u16 Asm[128 * 64];
  __shared__ u16 Bsm[128 * 64];
  const int tid = threadIdx.x;
  const int lane = tid & 63;
  const int wid = tid >> 6;
  const int wr = wid >> 1, wc = wid & 1;
  const int m0 = blockIdx.x * 128;
  const int n0 = blockIdx.y * 128;
  const int lrow = lane & 15;
  const int kgrp = (lane >> 4) * 8;

  f32x4 acc[4][4];
#pragma unroll
  for (int i = 0; i < 4; ++i)
#pragma unroll
    for (int j = 0; j < 4; ++j)
#pragma unroll
      for (int r = 0; r < 4; ++r) acc[i][j][r] = 0.f;

  for (int kt = 0; kt < HID / 64; ++kt) {
    __syncthreads();
#pragma unroll
    for (int it = 0; it < 4; ++it) {
      const int off = it * 4096 + tid * 16;
      const int row = off >> 7;
      const int col = (off & 127) >> 1;
      gload16(A  + (size_t)(m0 + row) * HID + kt * 64 + col, (char*)Asm + off);
      gload16(Bt + (size_t)(n0 + row) * HID + kt * 64 + col, (char*)Bsm + off);
    }
    __syncthreads();
#pragma unroll
    for (int kk = 0; kk < 2; ++kk) {
      bf16x8 af[4], bfr[4];
#pragma unroll
      for (int i = 0; i < 4; ++i) {
        af[i]  = *(const bf16x8*)(Asm + (size_t)(wr * 64 + i * 16 + lrow) * 64 + kk * 32 + kgrp);
        bfr[i] = *(const bf16x8*)(Bsm + (size_t)(wc * 64 + i * 16 + lrow) * 64 + kk * 32 + kgrp);
      }
#pragma unroll
      for (int i = 0; i < 4; ++i)
#pragma unroll
        for (int j = 0; j < 4; ++j)
          acc[i][j] = __builtin_amdgcn_mfma_f32_16x16x32_bf16(af[i], bfr[j], acc[i][j], 0, 0, 0);
    }
  }

#pragma unroll
  for (int i = 0; i < 4; ++i) {
#pragma unroll
    for (int j = 0; j < 4; ++j) {
      const int rbase = m0 + wr * 64 + i * 16 + (lane >> 4) * 4;
      const int n = n0 + wc * 64 + j * 16 + lrow;
      const float bv = bias[n];
#pragma unroll
      for (int r = 0; r < 4; ++r)
        O[(size_t)(rbase + r) * HID + n] = acc[i][j][r] + bv;
    }
  }
}

// ------------------------------------------------------------ flash attention
// Q,K: [B,NH,S,HD] bf16; Vt: [B,NH,HD,S] bf16; msk: [B,S] f32
// ctx out: [B,S,HID] bf16
// Fixed-max softmax (uniform exp(-m) cancels exactly in P.V / P.1 for mask==1;
// masked cols exp->0): no max reduction, no rescale; row-sum l via ones-column
// MFMA on the same bf16 P as the numerator (self-consistent).
// K/V LDS tiles XOR-swizzled (byte ^= (row&7)<<4) via pre-swizzled global src.
__global__ __launch_bounds__(256) void attn_kernel(const u16* __restrict__ Q,
                                                   const u16* __restrict__ K,
                                                   const u16* __restrict__ Vt,
                                                   const float* __restrict__ msk,
                                                   u16* __restrict__ ctx) {
  __shared__ u16 Ks[64 * 64];       // [key][d], swizzled
  __shared__ u16 Vs[64 * 64];       // [d][key], swizzled
  __shared__ u16 Ps[4][32 * 72];    // per-wave P, padded rows
  const int bh = blockIdx.y;
  const int b = bh >> 4, h = bh & 15;
  const int q0 = blockIdx.x * 128;
  const int tid = threadIdx.x, lane = tid & 63, wid = tid >> 6;
  const int lrow = lane & 15;
  const int kgrp = (lane >> 4) * 8;
  const u16* Qp = Q + (size_t)bh * SEQ * HD;
  const u16* Kp = K + (size_t)bh * SEQ * HD;
  const u16* Vp = Vt + (size_t)bh * HD * SEQ;

  // ones B-fragment (bf16 1.0) for row-sum MFMA
  bf16x8 vones;
#pragma unroll
  for (int i = 0; i < 8; ++i) vones[i] = (short)0x3F80;

  // Q fragments in registers, reused for all key tiles. Wave owns 32 q-rows.
  bf16x8 qf[2][2];
#pragma unroll
  for (int rf = 0; rf < 2; ++rf)
#pragma unroll
    for (int kk = 0; kk < 2; ++kk)
      qf[rf][kk] = *(const bf16x8*)(Qp + (size_t)(q0 + wid * 32 + rf * 16 + lrow) * HD + kk * 32 + kgrp);

  f32x4 acc[2][4], acc_l[2];
#pragma unroll
  for (int rf = 0; rf < 2; ++rf) {
#pragma unroll
    for (int r = 0; r < 4; ++r) acc_l[rf][r] = 0.f;
#pragma unroll
    for (int df = 0; df < 4; ++df)
#pragma unroll
      for (int r = 0; r < 4; ++r) acc[rf][df][r] = 0.f;
  }

  for (int s0 = 0; s0 < SEQ; s0 += 64) {
    __syncthreads();  // all waves done with previous K/V tiles
#pragma unroll
    for (int it = 0; it < 2; ++it) {
      const int off = it * 4096 + tid * 16;
      const int row = off >> 7;
      const int w = off & 127;
      const int col = (w ^ ((row & 7) << 4)) >> 1;   // inverse-swizzled source
      gload16(Kp + (size_t)(s0 + row) * HD + col, (char*)Ks + off);
      gload16(Vp + (size_t)row * SEQ + s0 + col, (char*)Vs + off);
    }
    __syncthreads();  // staging complete (barrier drains vmcnt)

    // S = Q K^T
    f32x4 sf[2][4];
#pragma unroll
    for (int rf = 0; rf < 2; ++rf)
#pragma unroll
      for (int c = 0; c < 4; ++c)
#pragma unroll
        for (int r = 0; r < 4; ++r) sf[rf][c][r] = 0.f;
#pragma unroll
    for (int kk = 0; kk < 2; ++kk) {
      bf16x8 kf[4];
#pragma unroll
      for (int c = 0; c < 4; ++c) {
        const int row = c * 16 + lrow;
        const int byteoff = row * 128 + ((kk * 64 + (lane >> 4) * 16) ^ ((row & 7) << 4));
        kf[c] = *(const bf16x8*)((const char*)Ks + byteoff);
      }
#pragma unroll
      for (int rf = 0; rf < 2; ++rf)
#pragma unroll
        for (int c = 0; c < 4; ++c)
          sf[rf][c] = __builtin_amdgcn_mfma_f32_16x16x32_bf16(qf[rf][kk], kf[c], sf[rf][c], 0, 0, 0);
    }

    // additive mask (column-wise)
    float addm[4];
#pragma unroll
    for (int c = 0; c < 4; ++c)
      addm[c] = (1.0f - msk[b * SEQ + s0 + c * 16 + lrow]) * -10000.0f;

    // fixed-max softmax: P = exp(scale*S + mask); write bf16 P to per-wave LDS
#pragma unroll
    for (int rf = 0; rf < 2; ++rf) {
#pragma unroll
      for (int c = 0; c < 4; ++c)
#pragma unroll
        for (int r = 0; r < 4; ++r)
          sf[rf][c][r] = __expf(sf[rf][c][r] * ATT_SCALE + addm[c]);
#pragma unroll
      for (int r = 0; r < 4; ++r) {
        const int row = rf * 16 + (lane >> 4) * 4 + r;
        const unsigned w01 = pk2(sf[rf][0][r], sf[rf][1][r]);
        const unsigned w23 = pk2(sf[rf][2][r], sf[rf][3][r]);
        u16* base = &Ps[wid][(size_t)row * 72 + lrow];
        base[0]  = (u16)w01;
        base[16] = (u16)(w01 >> 16);
        base[32] = (u16)w23;
        base[48] = (u16)(w23 >> 16);
      }
    }

    // ctx += P V ; l += P @ 1  (A-frags re-read from own wave's Ps)
#pragma unroll
    for (int kk = 0; kk < 2; ++kk) {
      bf16x8 pf[2], vf[4];
#pragma unroll
      for (int rf = 0; rf < 2; ++rf)
        pf[rf] = *(const bf16x8*)(&Ps[wid][(size_t)(rf * 16 + lrow) * 72 + kk * 32 + kgrp]);
#pragma unroll
      for (int df = 0; df < 4; ++df) {
        const int row = df * 16 + lrow;
        const int byteoff = row * 128 + ((kk * 64 + (lane >> 4) * 16) ^ ((row & 7) << 4));
        vf[df] = *(const bf16x8*)((const char*)Vs + byteoff);
      }
#pragma unroll
      for (int rf = 0; rf < 2; ++rf) {
#pragma unroll
        for (int df = 0; df < 4; ++df)
          acc[rf][df] = __builtin_amdgcn_mfma_f32_16x16x32_bf16(pf[rf], vf[df], acc[rf][df], 0, 0, 0);
        acc_l[rf] = __builtin_amdgcn_mfma_f32_16x16x32_bf16(pf[rf], vones, acc_l[rf], 0, 0, 0);
      }
    }
  }

  // normalize + store ctx in [B,S,HID] bf16
#pragma unroll
  for (int rf = 0; rf < 2; ++rf) {
    f32x4 rl;
#pragma unroll
    for (int r = 0; r < 4; ++r) rl[r] = 1.0f / acc_l[rf][r];
#pragma unroll
    for (int df = 0; df < 4; ++df)
#pragma unroll
      for (int r = 0; r < 4; ++r) {
        const int s = q0 + wid * 32 + rf * 16 + (lane >> 4) * 4 + r;
        const int d = df * 16 + lrow;
        ctx[((size_t)(b * SEQ + s)) * HID + h * HD + d] = f2b(acc[rf][df][r] * rl[r]);
      }
  }
}

// ---------------------------------------------------------------- launch
extern "C" void kernel_launch(void* const* d_in, const int* in_sizes, int n_in,
                              void* d_out, int out_size, void* d_ws, size_t ws_size,
                              hipStream_t stream) {
  const float* X    = (const float*)d_in[0];
  const float* msk  = (const float*)d_in[1];
  const float* Wq   = (const float*)d_in[2];
  const float* bq   = (const float*)d_in[3];
  const float* Wk   = (const float*)d_in[4];
  const float* bk   = (const float*)d_in[5];
  const float* Wv   = (const float*)d_in[6];
  const float* bv   = (const float*)d_in[7];
  const float* Wo   = (const float*)d_in[8];
  const float* bo   = (const float*)d_in[9];
  float* out = (float*)d_out;
  char* ws = (char*)d_ws;

  const size_t MB = 1u << 20;
  u16* XB   = (u16*)(ws);              //  8 MB  [MROWS][HID]
  u16* WTq  = (u16*)(ws +  8 * MB);    //  2 MB each; WTq|WTk|WTv contiguous
  u16* WTk  = (u16*)(ws + 10 * MB);
  u16* WTv  = (u16*)(ws + 12 * MB);
  u16* WTo  = (u16*)(ws + 14 * MB);
  u16* Qb   = (u16*)(ws + 16 * MB);    //  8 MB  [B,NH,S,HD]
  u16* Kb   = (u16*)(ws + 24 * MB);    //  8 MB  [B,NH,S,HD]
  u16* VTb  = (u16*)(ws + 32 * MB);    //  8 MB  [B,NH,HD,S]
  u16* CTXb = (u16*)(ws + 40 * MB);    //  8 MB  [B,S,HID]

  castx_kernel<<<dim3(MROWS * HID / 4 / 256), dim3(256), 0, stream>>>(X, XB);
  wtrans4_kernel<<<dim3(HID / 32, HID / 32, 4), dim3(32, 8), 0, stream>>>(
      Wq, Wk, Wv, Wo, WTq, WTk, WTv, WTo);

  gemm_qkv_kernel<<<dim3(MROWS / 128, 3 * HID / 128), dim3(256), 0, stream>>>(
      XB, WTq, bq, bk, bv, Qb, Kb, VTb);

  attn_kernel<<<dim3(SEQ / 128, BATCH * NH), dim3(256), 0, stream>>>(Qb, Kb, VTb, msk, CTXb);

  gemm_out_kernel<<<dim3(MROWS / 128, HID / 128), dim3(256), 0, stream>>>(CTXb, WTo, bo, out);
}